// Round 11
// baseline (81.330 us; speedup 1.0000x reference)
//
#include <hip/hip_runtime.h>

typedef _Float16 f16;
typedef _Float16 f16x8 __attribute__((ext_vector_type(8)));
typedef float    f32x4 __attribute__((ext_vector_type(4)));

#define HO 62
#define WO 62

// Pixel record padded 16 -> 24 f16 (48 B): LDS bank stride 12 -> 2-way
// aliasing (free) instead of 4-way on every b128 read/write.
#define RECSZ  24
#define ROWST  (18 * RECSZ)            // 432 f16 per tile row
#define SLICE  (10 * ROWST + RECSZ)    // 4344 f16; last record zeroed (pad)

// ---------- prep: per-lane MFMA B-fragment image (runs once) ----------
// ws[q*64 + lane], q = ki*2 + kjp.
__global__ __launch_bounds__(384) void kan_prep(
    const float* __restrict__ bw, const float* __restrict__ sw,
    const float* __restrict__ sc, f16x8* __restrict__ ws)
{
    const int tid  = threadIdx.x;        // 0..383
    const int lane = tid & 63;
    const int q    = tid >> 6;           // 0..5
    const int ki   = q >> 1;
    const int kjp  = q & 1;
    const int nn   = lane & 15;
    const int kb   = lane >> 4;
    f16x8 bf;
    #pragma unroll
    for (int e = 0; e < 8; ++e) {
        const int k    = kb * 8 + e;
        const int kj   = kjp * 2 + (k >> 4);
        const int slot = k & 15;
        float wv = 0.0f;
        if (nn < 8 && kj < 3 && slot < 9) {
            const int kk = ki * 3 + kj;
            wv = (slot == 0) ? bw[nn * 9 + kk]
                             : sw[(nn * 9 + kk) * 8 + (slot - 1)] * sc[nn * 9 + kk];
        }
        bf[e] = (f16)wv;
    }
    ws[q * 64 + lane] = bf;
}

// ---------- main: barrier-free wave-private MFMA KAN conv ----------
// 1024 blocks x 256 thr (4 waves). Wave unit = (plane, chunk, col-half):
// wave processes 2 col-tiles; tile t+1's x-loads are issued BEFORE tile t's
// stage2 (latency hidden under MFMA). No __syncthreads anywhere.
__global__ __launch_bounds__(256, 4) void kan_main(
    const float* __restrict__ x,     // (256, 64, 64)
    const float* __restrict__ grid_, // (9, 12) uniform knots
    const f16x8* __restrict__ ws,    // prep output
    float* __restrict__ out)         // (256*8, 62, 62)
{
    __shared__ __align__(16) f16 feat[4 * SLICE];   // 34.75 KB

    const int tid  = threadIdx.x;
    const int lane = tid & 63;
    const int w    = tid >> 6;
    f16* wfeat = &feat[w * SLICE];

    const int unit  = blockIdx.x * 4 + w;   // 0..4095
    const int plane = unit >> 4;
    const int chunk = (unit >> 1) & 7;
    const int sh    = unit & 1;             // col-half: tiles 2sh, 2sh+1
    const int r0    = chunk * 8;            // output rows r0..r0+7 (masked >=62)

    // ---- B fragments: 6 coalesced 16B loads
    f16x8 bfrag[3][2];
    #pragma unroll
    for (int q = 0; q < 6; ++q)
        bfrag[q >> 1][q & 1] = ws[q * 64 + lane];

    // ---- zero the slice pad record
    {
        f16x8 z = {(f16)0.f,(f16)0.f,(f16)0.f,(f16)0.f,
                   (f16)0.f,(f16)0.f,(f16)0.f,(f16)0.f};
        if (lane < 3) *(f16x8*)&wfeat[10 * ROWST + lane * 8] = z;
    }

    const float g0    = grid_[0];
    const float inv_h = 1.0f / (grid_[1] - grid_[0]);
    const float* xp   = x + (size_t)plane * 4096;

    // per-lane tile-pixel geometry (same for both tiles except c0)
    int prow[3], pcol[3];
    #pragma unroll
    for (int it = 0; it < 3; ++it) {
        const int p = it * 64 + lane;
        prow[it] = p / 18;
        pcol[it] = p - prow[it] * 18;
    }

    // ---- prefetch x for tile 0
    float xv[3];
    {
        const int c0 = (2 * sh) * 16;
        #pragma unroll
        for (int it = 0; it < 3; ++it) {
            int gy = r0 + prow[it]; gy = (gy < 64) ? gy : 63;
            int gx = c0 + pcol[it]; gx = (gx < 64) ? gx : 63;
            xv[it] = xp[gy * 64 + gx];
        }
    }

    const int mI    = lane & 15;    // A row = out col; D col = v (same bits)
    const int kb    = lane >> 4;
    const int nn    = mI;
    const int khalf = kb & 1;
    const int cAdd  = kb >> 1;
    const int aBase = (mI + cAdd) * RECSZ + khalf * 8;

    #pragma unroll
    for (int t = 0; t < 2; ++t) {
        const int c0 = (2 * sh + t) * 16;

        // ---- stage 1: features for this tile (wave-private LDS)
        #pragma unroll
        for (int it = 0; it < 3; ++it) {
            const int p = it * 64 + lane;
            if (p < 180) {
                const float xvv = xv[it];
                const float si = xvv / (1.0f + __expf(-xvv));
                const float u  = (xvv - g0) * inv_h;
                int j = (int)floorf(u);
                j = (j < 3) ? 3 : ((j > 7) ? 7 : j);
                const float tt  = u - (float)j;
                const float omt = 1.0f - tt;
                const float t2  = tt * tt;
                const float t3  = t2 * tt;
                const float c6  = 1.0f / 6.0f;
                const float bv0 = omt * omt * omt * c6;
                const float bv1 = (3.0f * t3 - 6.0f * t2 + 4.0f) * c6;
                const float bv2 = (-3.0f * t3 + 3.0f * t2 + 3.0f * tt + 1.0f) * c6;
                const float bv3 = t3 * c6;

                f16* fp = &wfeat[p * RECSZ];
                f16x8 z0 = {(f16)si, (f16)0.f, (f16)0.f, (f16)0.f,
                            (f16)0.f, (f16)0.f, (f16)0.f, (f16)0.f};
                f16x8 z1 = {(f16)0.f, (f16)0.f, (f16)0.f, (f16)0.f,
                            (f16)0.f, (f16)0.f, (f16)0.f, (f16)0.f};
                *(f16x8*)fp       = z0;          // slots 0-7 (slot0 = silu)
                *(f16x8*)(fp + 8) = z1;          // slots 8-15
                fp[j - 2] = (f16)bv0;            // scatter slots 1..8
                fp[j - 1] = (f16)bv1;
                fp[j]     = (f16)bv2;
                fp[j + 1] = (f16)bv3;
            }
        }

        // ---- issue next tile's x-loads NOW (hidden under stage 2)
        if (t == 0) {
            const int c1 = (2 * sh + 1) * 16;
            #pragma unroll
            for (int it = 0; it < 3; ++it) {
                int gy = r0 + prow[it]; gy = (gy < 64) ? gy : 63;
                int gx = c1 + pcol[it]; gx = (gx < 64) ? gx : 63;
                xv[it] = xp[gy * 64 + gx];
            }
        }

        // ---- stage 2: 8 output rows x 16 cols x 8 v via 6 MFMAs/row
        f16x8 af[3][2];                 // rolling A rows (row r at af[r % 3])
        #pragma unroll
        for (int kjp = 0; kjp < 2; ++kjp) {
            af[0][kjp] = *(const f16x8*)&wfeat[aBase + kjp * (2 * RECSZ) + 0 * ROWST];
            af[1][kjp] = *(const f16x8*)&wfeat[aBase + kjp * (2 * RECSZ) + 1 * ROWST];
        }

        #pragma unroll
        for (int i = 0; i < 8; ++i) {
            #pragma unroll
            for (int kjp = 0; kjp < 2; ++kjp)
                af[(i + 2) % 3][kjp] =
                    *(const f16x8*)&wfeat[aBase + kjp * (2 * RECSZ) + (i + 2) * ROWST];

            f32x4 acc = {0.f, 0.f, 0.f, 0.f};
            #pragma unroll
            for (int ki = 0; ki < 3; ++ki)
                #pragma unroll
                for (int kjp = 0; kjp < 2; ++kjp)
                    acc = __builtin_amdgcn_mfma_f32_16x16x32_f16(
                              af[(i + ki) % 3][kjp], bfrag[ki][kjp], acc, 0, 0, 0);

            const int ho = r0 + i;
            if (nn < 8 && ho < HO) {
                const int cb = c0 + kb * 4;
                float* po = out + ((size_t)(plane * 8 + nn) * (HO * WO)) + ho * WO + cb;
                if (cb + 3 < WO) {
                    float2 lo = {acc[0], acc[1]};
                    float2 hi = {acc[2], acc[3]};
                    *(float2*)po       = lo;
                    *(float2*)(po + 2) = hi;
                } else {
                    #pragma unroll
                    for (int q = 0; q < 4; ++q)
                        if (cb + q < WO) po[q] = acc[q];
                }
            }
        }
    }
}

extern "C" void kernel_launch(void* const* d_in, const int* in_sizes, int n_in,
                              void* d_out, int out_size, void* d_ws, size_t ws_size,
                              hipStream_t stream) {
    const float* x    = (const float*)d_in[0];
    const float* grid = (const float*)d_in[1];
    const float* bw   = (const float*)d_in[2];
    const float* sw   = (const float*)d_in[3];
    const float* sc   = (const float*)d_in[4];
    float* out = (float*)d_out;
    f16x8* ws  = (f16x8*)d_ws;

    kan_prep<<<1, 384, 0, stream>>>(bw, sw, sc, ws);
    kan_main<<<1024, 256, 0, stream>>>(x, grid, ws, out);
}